// Round 3
// baseline (188.185 us; speedup 1.0000x reference)
//
#include <hip/hip_runtime.h>
#include <math.h>

#define CI 12
#define NHID 15
#define NBLK 6144                 // 8*3*16*16 image blocks of 32x32
#define NPIX (NBLK * 1024)

typedef int i32x2 __attribute__((ext_vector_type(2)));

// f32 pair -> packed f16 (RTZ) via v_cvt_pkrtz_f16_f32 (1 VALU inst)
static __device__ __forceinline__ int h2pack(float lo, float hi) {
    auto h = __builtin_amdgcn_cvt_pkrtz(lo, hi);   // half2
    int r;
    __builtin_memcpy(&r, &h, 4);
    return r;
}

// ---- hand-scheduled hot-loop asm ------------------------------------------
// MLP in f16 via v_mfma_f32_16x16x16_f16 (A = 2 regs -> 32 AGPRs for 16
// layers). 8 independent pixel chains per asm block (2 row-pairs fused) so
// every MFMA-D -> activation gap is >100 cy and the layer-0/epilogue drain
// is amortized 2x better. K map: k0..11 channels, k12 bias (A[12][12]=1.0
// self-regenerates the 1.0 bias operand through the activation), k13..15=0.
// Pinned regs: zeros v32-35; B-frags A..H v36-51 (pairs); D-quads A..H
// v52-83; tmp v84/85. Weights: 16 AGPR pairs. s21 = f16(0.01) broadcast.
#define LKx(D0,D1,D2,D3,B0,B1) \
  "v_cvt_pkrtz_f16_f32 " B0 ", " D0 ", " D1 "\n" \
  "v_cvt_pkrtz_f16_f32 " B1 ", " D2 ", " D3 "\n" \
  "v_pk_mul_f16 v84, s21, " B0 "\n" \
  "v_pk_mul_f16 v85, s21, " B1 "\n" \
  "v_pk_max_f16 " B0 ", " B0 ", v84\n" \
  "v_pk_max_f16 " B1 ", " B1 ", v85\n"

#define LKA LKx("v52","v53","v54","v55","v36","v37")
#define LKB LKx("v56","v57","v58","v59","v38","v39")
#define LKC LKx("v60","v61","v62","v63","v40","v41")
#define LKD LKx("v64","v65","v66","v67","v42","v43")
#define LKE LKx("v68","v69","v70","v71","v44","v45")
#define LKF LKx("v72","v73","v74","v75","v46","v47")
#define LKG LKx("v76","v77","v78","v79","v48","v49")
#define LKH LKx("v80","v81","v82","v83","v50","v51")

#define MFA(w) "v_mfma_f32_16x16x16_f16 v[52:55], %[" w "], v[36:37], v[32:35]\n"
#define MFB(w) "v_mfma_f32_16x16x16_f16 v[56:59], %[" w "], v[38:39], v[32:35]\n"
#define MFC(w) "v_mfma_f32_16x16x16_f16 v[60:63], %[" w "], v[40:41], v[32:35]\n"
#define MFD(w) "v_mfma_f32_16x16x16_f16 v[64:67], %[" w "], v[42:43], v[32:35]\n"
#define MFE(w) "v_mfma_f32_16x16x16_f16 v[68:71], %[" w "], v[44:45], v[32:35]\n"
#define MFF(w) "v_mfma_f32_16x16x16_f16 v[72:75], %[" w "], v[46:47], v[32:35]\n"
#define MFG(w) "v_mfma_f32_16x16x16_f16 v[76:79], %[" w "], v[48:49], v[32:35]\n"
#define MFH(w) "v_mfma_f32_16x16x16_f16 v[80:83], %[" w "], v[50:51], v[32:35]\n"

#define LAYER(w) \
  LKA LKB MFA(w) LKC MFB(w) LKD MFC(w) LKE MFD(w) \
  LKF MFE(w) LKG MFF(w) LKH MFG(w) "s_nop 1\n" MFH(w)

__global__ __launch_bounds__(256, 4) void codec_main(
    const float* __restrict__ x,
    const float* __restrict__ Wh,   // [15][12][12]
    const float* __restrict__ bh,   // [15][12]
    const float* __restrict__ Wo,   // [12]
    const float* __restrict__ bo,   // [1]
    float* __restrict__ out,        // [1 + NPIX]
    float* __restrict__ loss_acc)   // [1] pre-zeroed
{
    __shared__ float tile[36 * 37]; // 32x32 + 2-halo, +1 col pad
    __shared__ float stage[4][256]; // per-wave delta staging
    __shared__ float wsum[4];

    const int n    = blockIdx.x;
    const int tid  = threadIdx.x;   // 0..255
    const int lane = tid & 63;
    const int wv   = tid >> 6;      // wave 0..3
    const int t    = lane & 15;
    const int q    = lane >> 4;

    // ---- stage image block into LDS (zero halo) ----
    {
        const int col = tid & 31;
        const int r0  = tid >> 5;
        #pragma unroll
        for (int i = 0; i < 6; ++i) {
            int idx = tid + i * 256;
            if (idx < 36 * 37) tile[idx] = 0.0f;
        }
        __syncthreads();
        const int bc  = n >> 8;
        const int blk = n & 255;
        const int by  = blk >> 4;
        const int bx  = blk & 15;
        #pragma unroll
        for (int p = 0; p < 4; ++p) {
            const int row = r0 + 8 * p;
            tile[(row + 2) * 37 + col + 2] =
                x[((size_t)bc * 512 + (size_t)(by * 32 + row)) * 512
                  + (size_t)(bx * 32 + col)];
        }
        __syncthreads();
    }

    // ---- weight A-frags (K=16): lane 16q+t = A[m=t][k=4q+j], j=0..3 ----
    i32x2 wq[16];
    #pragma unroll
    for (int l = 0; l < NHID; ++l) {
        int w0 = 0, w1 = 0;
        if (q < 3 && t < CI) {
            float4 w = *(const float4*)(Wh + l * (CI * CI) + t * CI + 4 * q);
            w0 = h2pack(w.x, w.y);
            w1 = h2pack(w.z, w.w);
        }
        if (q == 3 && t < CI)  w0 = h2pack(bh[l * CI + t], 0.f);
        if (q == 3 && t == CI) w0 = 0x3C00;            // A[12][12] = 1.0
        wq[l] = (i32x2){ w0, w1 };
    }
    {
        int w0 = 0, w1 = 0;
        if (t == 0 && q < 3) {
            float4 w = *(const float4*)(Wo + 4 * q);
            w0 = h2pack(w.x, w.y);
            w1 = h2pack(w.z, w.w);
        }
        if (t == 0 && q == 3) w0 = h2pack(bo[0], 0.f); // output bias at k=12
        wq[15] = (i32x2){ w0, w1 };
    }

    // ---- per-lane feature offsets (elements): channel c=4q+r at (dy,dx) ----
    const int sh8  = q * 8;
    const int off0 = (int)(signed char)((0x00DCB8B4u >> sh8) & 0xFFu);
    const int off1 = (int)(signed char)((0x00DDD9B5u >> sh8) & 0xFFu);
    const int off2 = (int)(signed char)((0x00FEDAB6u >> sh8) & 0xFFu);
    const int off3 = (int)(signed char)((0x00FFDBB7u >> sh8) & 0xFFu);
    const bool q3  = (q == 3);

    int e = (wv * 8 + 2) * 37 + (t + 2);             // row 8wv, half 0

    float d2 = 0.0f;
    #pragma unroll 1
    for (int yi = 0; yi < 2; ++yi) {
        // 8 chains: (row r..r+3) x (half 0: +0, half 1: +16); rows step 37.
        // q==3 lanes carry the bias slot: word0 = f16(1.0) at k=12.
        const int fa0 = q3 ? 0x3C00 : h2pack(tile[e + off0],       tile[e + off1]);
        const int fa1 = q3 ? 0      : h2pack(tile[e + off2],       tile[e + off3]);
        const int fb0 = q3 ? 0x3C00 : h2pack(tile[e + off0 + 16],  tile[e + off1 + 16]);
        const int fb1 = q3 ? 0      : h2pack(tile[e + off2 + 16],  tile[e + off3 + 16]);
        const int fc0 = q3 ? 0x3C00 : h2pack(tile[e + off0 + 37],  tile[e + off1 + 37]);
        const int fc1 = q3 ? 0      : h2pack(tile[e + off2 + 37],  tile[e + off3 + 37]);
        const int fd0 = q3 ? 0x3C00 : h2pack(tile[e + off0 + 53],  tile[e + off1 + 53]);
        const int fd1 = q3 ? 0      : h2pack(tile[e + off2 + 53],  tile[e + off3 + 53]);
        const int fe0 = q3 ? 0x3C00 : h2pack(tile[e + off0 + 74],  tile[e + off1 + 74]);
        const int fe1 = q3 ? 0      : h2pack(tile[e + off2 + 74],  tile[e + off3 + 74]);
        const int ff0 = q3 ? 0x3C00 : h2pack(tile[e + off0 + 90],  tile[e + off1 + 90]);
        const int ff1 = q3 ? 0      : h2pack(tile[e + off2 + 90],  tile[e + off3 + 90]);
        const int fg0 = q3 ? 0x3C00 : h2pack(tile[e + off0 + 111], tile[e + off1 + 111]);
        const int fg1 = q3 ? 0      : h2pack(tile[e + off2 + 111], tile[e + off3 + 111]);
        const int fh0 = q3 ? 0x3C00 : h2pack(tile[e + off0 + 127], tile[e + off1 + 127]);
        const int fh1 = q3 ? 0      : h2pack(tile[e + off2 + 127], tile[e + off3 + 127]);

        float pA, pB, pC, pD, pE, pF, pG, pH;
        asm volatile(
            "s_mov_b32 s21, 0x211f211f\n"
            "v_mov_b32 v32, 0\n" "v_mov_b32 v33, 0\n"
            "v_mov_b32 v34, 0\n" "v_mov_b32 v35, 0\n"
            "v_mov_b32 v36, %[fa0]\n" "v_mov_b32 v37, %[fa1]\n"
            "v_mov_b32 v38, %[fb0]\n" "v_mov_b32 v39, %[fb1]\n"
            "v_mov_b32 v40, %[fc0]\n" "v_mov_b32 v41, %[fc1]\n"
            "v_mov_b32 v42, %[fd0]\n" "v_mov_b32 v43, %[fd1]\n"
            "v_mov_b32 v44, %[fe0]\n" "v_mov_b32 v45, %[fe1]\n"
            "v_mov_b32 v46, %[ff0]\n" "v_mov_b32 v47, %[ff1]\n"
            "v_mov_b32 v48, %[fg0]\n" "v_mov_b32 v49, %[fg1]\n"
            "v_mov_b32 v50, %[fh0]\n" "v_mov_b32 v51, %[fh1]\n"
            MFA("w0") MFB("w0") MFC("w0") MFD("w0")
            MFE("w0") MFF("w0") MFG("w0") MFH("w0")
            "s_nop 7\n"
            LAYER("w1")  LAYER("w2")  LAYER("w3")  LAYER("w4")
            LAYER("w5")  LAYER("w6")  LAYER("w7")  LAYER("w8")
            LAYER("w9")  LAYER("w10") LAYER("w11") LAYER("w12")
            LAYER("w13") LAYER("w14") LAYER("w15")
            "v_mov_b32 %[pA], v52\n" "v_mov_b32 %[pB], v56\n"
            "v_mov_b32 %[pC], v60\n" "v_mov_b32 %[pD], v64\n"
            "s_nop 7\n"
            "v_mov_b32 %[pE], v68\n" "v_mov_b32 %[pF], v72\n"
            "s_nop 7\n"
            "v_mov_b32 %[pG], v76\n"
            "s_nop 3\n"
            "v_mov_b32 %[pH], v80\n"
            : [pA] "=v"(pA), [pB] "=v"(pB), [pC] "=v"(pC), [pD] "=v"(pD),
              [pE] "=v"(pE), [pF] "=v"(pF), [pG] "=v"(pG), [pH] "=v"(pH)
            : [w0] "a"(wq[0]),  [w1] "a"(wq[1]),  [w2] "a"(wq[2]),
              [w3] "a"(wq[3]),  [w4] "a"(wq[4]),  [w5] "a"(wq[5]),
              [w6] "a"(wq[6]),  [w7] "a"(wq[7]),  [w8] "a"(wq[8]),
              [w9] "a"(wq[9]),  [w10] "a"(wq[10]), [w11] "a"(wq[11]),
              [w12] "a"(wq[12]), [w13] "a"(wq[13]), [w14] "a"(wq[14]),
              [w15] "a"(wq[15]),
              [fa0] "v"(fa0), [fa1] "v"(fa1), [fb0] "v"(fb0), [fb1] "v"(fb1),
              [fc0] "v"(fc0), [fc1] "v"(fc1), [fd0] "v"(fd0), [fd1] "v"(fd1),
              [fe0] "v"(fe0), [fe1] "v"(fe1), [ff0] "v"(ff0), [ff1] "v"(ff1),
              [fg0] "v"(fg0), [fg1] "v"(fg1), [fh0] "v"(fh0), [fh1] "v"(fh1)
            : "s21",
              "v32","v33","v34","v35","v36","v37","v38","v39",
              "v40","v41","v42","v43","v44","v45","v46","v47",
              "v48","v49","v50","v51","v52","v53","v54","v55",
              "v56","v57","v58","v59","v60","v61","v62","v63",
              "v64","v65","v66","v67","v68","v69","v70","v71",
              "v72","v73","v74","v75","v76","v77","v78","v79",
              "v80","v81","v82","v83","v84","v85");

        // raw pixels loaded after the asm to cap live regs at asm entry
        const float vA = tile[e],       vB = tile[e + 16];
        const float vC = tile[e + 37],  vD = tile[e + 53];
        const float vE = tile[e + 74],  vF = tile[e + 90];
        const float vG = tile[e + 111], vH = tile[e + 127];

        if (lane < 16) {                   // D row 0 = prediction, lanes 0..15
            const float qA = fminf(fmaxf(pA, -1.0f), 1.0f);
            const float uA = vA - qA + 1.0f;
            const float dA = uA - ((uA < 2.0f) ? 1.0f : 3.0f); // fmod(u,2)-1
            const float qB = fminf(fmaxf(pB, -1.0f), 1.0f);
            const float uB = vB - qB + 1.0f;
            const float dB = uB - ((uB < 2.0f) ? 1.0f : 3.0f);
            const float qC = fminf(fmaxf(pC, -1.0f), 1.0f);
            const float uC = vC - qC + 1.0f;
            const float dC = uC - ((uC < 2.0f) ? 1.0f : 3.0f);
            const float qD = fminf(fmaxf(pD, -1.0f), 1.0f);
            const float uD = vD - qD + 1.0f;
            const float dD = uD - ((uD < 2.0f) ? 1.0f : 3.0f);
            const float qE = fminf(fmaxf(pE, -1.0f), 1.0f);
            const float uE = vE - qE + 1.0f;
            const float dE = uE - ((uE < 2.0f) ? 1.0f : 3.0f);
            const float qF = fminf(fmaxf(pF, -1.0f), 1.0f);
            const float uF = vF - qF + 1.0f;
            const float dF = uF - ((uF < 2.0f) ? 1.0f : 3.0f);
            const float qG = fminf(fmaxf(pG, -1.0f), 1.0f);
            const float uG = vG - qG + 1.0f;
            const float dG = uG - ((uG < 2.0f) ? 1.0f : 3.0f);
            const float qH = fminf(fmaxf(pH, -1.0f), 1.0f);
            const float uH = vH - qH + 1.0f;
            const float dH = uH - ((uH < 2.0f) ? 1.0f : 3.0f);
            const int r = 4 * yi;
            stage[wv][(r + 0) * 32 + t]      = dA;
            stage[wv][(r + 0) * 32 + 16 + t] = dB;
            stage[wv][(r + 1) * 32 + t]      = dC;
            stage[wv][(r + 1) * 32 + 16 + t] = dD;
            stage[wv][(r + 2) * 32 + t]      = dE;
            stage[wv][(r + 2) * 32 + 16 + t] = dF;
            stage[wv][(r + 3) * 32 + t]      = dG;
            stage[wv][(r + 3) * 32 + 16 + t] = dH;
            d2 = fmaf(dA, dA, fmaf(dB, dB, fmaf(dC, dC, fmaf(dD, dD, d2))));
            d2 = fmaf(dE, dE, fmaf(dF, dF, fmaf(dG, dG, fmaf(dH, dH, d2))));
        }
        e += 148;                           // four rows
    }

    // ---- coalesced delta store: wave's 256 floats = rows [8wv, 8wv+8) ----
    float* outp = out + 1 + (size_t)n * 1024 + wv * 256;
    #pragma unroll
    for (int j = 0; j < 4; ++j)
        outp[j * 64 + lane] = stage[wv][j * 64 + lane];

    // ---- loss reduction (d2 nonzero only in lanes 0..15) ----
    #pragma unroll
    for (int off = 8; off > 0; off >>= 1) d2 += __shfl_down(d2, off, 64);
    if (lane == 0) wsum[wv] = d2;
    __syncthreads();
    if (tid == 0) atomicAdd(loss_acc, wsum[0] + wsum[1] + wsum[2] + wsum[3]);
}

__global__ void codec_loss(const float* __restrict__ acc, float* __restrict__ out)
{
    out[0] = 255.0f * sqrtf(acc[0] / (float)NPIX);
}

extern "C" void kernel_launch(void* const* d_in, const int* in_sizes, int n_in,
                              void* d_out, int out_size, void* d_ws, size_t ws_size,
                              hipStream_t stream)
{
    const float* x  = (const float*)d_in[0];
    const float* Wh = (const float*)d_in[1];
    const float* bh = (const float*)d_in[2];
    const float* Wo = (const float*)d_in[3];
    const float* bo = (const float*)d_in[4];
    float* out = (float*)d_out;
    float* acc = (float*)d_ws;

    hipMemsetAsync(acc, 0, sizeof(float), stream);   // graph-capture safe
    codec_main<<<NBLK, 256, 0, stream>>>(x, Wh, bh, Wo, bo, out, acc);
    codec_loss<<<1, 1, 0, stream>>>(acc, out);
}

// Round 4
// 182.903 us; speedup vs baseline: 1.0289x; 1.0289x over previous
//
#include <hip/hip_runtime.h>
#include <math.h>

#define CI 12
#define NHID 15
#define NBLK 6144                 // 8*3*16*16 image blocks of 32x32
#define NPIX (NBLK * 1024)

typedef int i32x2 __attribute__((ext_vector_type(2)));

// f32 pair -> packed f16 (RTZ) via v_cvt_pkrtz_f16_f32 (1 VALU inst)
static __device__ __forceinline__ int h2pack(float lo, float hi) {
    auto h = __builtin_amdgcn_cvt_pkrtz(lo, hi);   // half2
    int r;
    __builtin_memcpy(&r, &h, 4);
    return r;
}

// ---- hand-scheduled hot-loop asm ------------------------------------------
// MLP in f16 via v_mfma_f32_16x16x16_f16 (A = 2 regs -> 32 AGPRs for 16
// layers). 4 independent pixel chains per asm block (proven R2 structure).
// K map: k0..11 channels, k12 bias (A[12][12]=1.0 self-regenerates the 1.0
// bias operand through the activation), k13..15 = 0.
// Pinned regs: zeros v32-35; B-frags A..D v36-43 (pairs); D-quads A..D
// v44-59; tmp v60/61. Weights: 16 AGPR pairs. s21 = f16(0.01) broadcast.
// Occupancy plan: launch_bounds(256,5) -> 102-reg budget forces compiler
// temps into v0..v31; arch ~64 + 32 AGPR = 96 -> 5 waves/SIMD (480<=512).
#define LKA \
  "v_cvt_pkrtz_f16_f32 v36, v44, v45\n" \
  "v_cvt_pkrtz_f16_f32 v37, v46, v47\n" \
  "v_pk_mul_f16 v60, s21, v36\n" \
  "v_pk_mul_f16 v61, s21, v37\n" \
  "v_pk_max_f16 v36, v36, v60\n" \
  "v_pk_max_f16 v37, v37, v61\n"
#define LKB \
  "v_cvt_pkrtz_f16_f32 v38, v48, v49\n" \
  "v_cvt_pkrtz_f16_f32 v39, v50, v51\n" \
  "v_pk_mul_f16 v60, s21, v38\n" \
  "v_pk_mul_f16 v61, s21, v39\n" \
  "v_pk_max_f16 v38, v38, v60\n" \
  "v_pk_max_f16 v39, v39, v61\n"
#define LKC \
  "v_cvt_pkrtz_f16_f32 v40, v52, v53\n" \
  "v_cvt_pkrtz_f16_f32 v41, v54, v55\n" \
  "v_pk_mul_f16 v60, s21, v40\n" \
  "v_pk_mul_f16 v61, s21, v41\n" \
  "v_pk_max_f16 v40, v40, v60\n" \
  "v_pk_max_f16 v41, v41, v61\n"
#define LKD \
  "v_cvt_pkrtz_f16_f32 v42, v56, v57\n" \
  "v_cvt_pkrtz_f16_f32 v43, v58, v59\n" \
  "v_pk_mul_f16 v60, s21, v42\n" \
  "v_pk_mul_f16 v61, s21, v43\n" \
  "v_pk_max_f16 v42, v42, v60\n" \
  "v_pk_max_f16 v43, v43, v61\n"

#define MFA(w) "v_mfma_f32_16x16x16_f16 v[44:47], %[" w "], v[36:37], v[32:35]\n"
#define MFB(w) "v_mfma_f32_16x16x16_f16 v[48:51], %[" w "], v[38:39], v[32:35]\n"
#define MFC(w) "v_mfma_f32_16x16x16_f16 v[52:55], %[" w "], v[40:41], v[32:35]\n"
#define MFD(w) "v_mfma_f32_16x16x16_f16 v[56:59], %[" w "], v[42:43], v[32:35]\n"

#define LAYER(w) LKA LKB MFA(w) LKC MFB(w) LKD MFC(w) "s_nop 1\n" MFD(w)

__global__ __launch_bounds__(256, 5) void codec_main(
    const float* __restrict__ x,
    const float* __restrict__ Wh,   // [15][12][12]
    const float* __restrict__ bh,   // [15][12]
    const float* __restrict__ Wo,   // [12]
    const float* __restrict__ bo,   // [1]
    float* __restrict__ out,        // [1 + NPIX]
    float* __restrict__ loss_acc)   // [1] pre-zeroed
{
    __shared__ float tile[36 * 37]; // 32x32 + 2-halo, +1 col pad
    __shared__ float stage[4][256]; // per-wave delta staging
    __shared__ float wsum[4];

    const int n    = blockIdx.x;
    const int tid  = threadIdx.x;   // 0..255
    const int lane = tid & 63;
    const int wv   = tid >> 6;      // wave 0..3
    const int t    = lane & 15;
    const int q    = lane >> 4;

    // ---- stage image block into LDS (zero halo) ----
    {
        const int col = tid & 31;
        const int r0  = tid >> 5;
        #pragma unroll
        for (int i = 0; i < 6; ++i) {
            int idx = tid + i * 256;
            if (idx < 36 * 37) tile[idx] = 0.0f;
        }
        __syncthreads();
        const int bc  = n >> 8;
        const int blk = n & 255;
        const int by  = blk >> 4;
        const int bx  = blk & 15;
        #pragma unroll
        for (int p = 0; p < 4; ++p) {
            const int row = r0 + 8 * p;
            tile[(row + 2) * 37 + col + 2] =
                x[((size_t)bc * 512 + (size_t)(by * 32 + row)) * 512
                  + (size_t)(bx * 32 + col)];
        }
        __syncthreads();
    }

    // ---- weight A-frags (K=16): lane 16q+t = A[m=t][k=4q+j], j=0..3 ----
    // q<3: channels; q==3: word0 = pack(bias, 0) (k=12), word1 = 0;
    // q==3,t==12 (hidden layers): identity 1.0 to self-propagate bias slot.
    i32x2 wq[16];
    #pragma unroll
    for (int l = 0; l < NHID; ++l) {
        int w0 = 0, w1 = 0;
        if (q < 3 && t < CI) {
            float4 w = *(const float4*)(Wh + l * (CI * CI) + t * CI + 4 * q);
            w0 = h2pack(w.x, w.y);
            w1 = h2pack(w.z, w.w);
        }
        if (q == 3 && t < CI)  w0 = h2pack(bh[l * CI + t], 0.f);
        if (q == 3 && t == CI) w0 = 0x3C00;            // A[12][12] = 1.0
        wq[l] = (i32x2){ w0, w1 };
    }
    {
        int w0 = 0, w1 = 0;
        if (t == 0 && q < 3) {
            float4 w = *(const float4*)(Wo + 4 * q);
            w0 = h2pack(w.x, w.y);
            w1 = h2pack(w.z, w.w);
        }
        if (t == 0 && q == 3) w0 = h2pack(bo[0], 0.f); // output bias at k=12
        wq[15] = (i32x2){ w0, w1 };
    }

    // ---- per-lane feature offsets (elements): channel c=4q+r at (dy,dx) ----
    const int sh8  = q * 8;
    const int off0 = (int)(signed char)((0x00DCB8B4u >> sh8) & 0xFFu);
    const int off1 = (int)(signed char)((0x00DDD9B5u >> sh8) & 0xFFu);
    const int off2 = (int)(signed char)((0x00FEDAB6u >> sh8) & 0xFFu);
    const int off3 = (int)(signed char)((0x00FFDBB7u >> sh8) & 0xFFu);
    const bool q3  = (q == 3);

    int e = (wv * 8 + 2) * 37 + (t + 2);             // row 8wv, half 0

    float d2 = 0.0f;
    #pragma unroll 1
    for (int yi = 0; yi < 4; ++yi) {
        // chains: A=(row r,half0) B=(r,half1) C=(r+1,half0) D=(r+1,half1)
        // q==3 lanes carry the bias slot: word0 = f16(1.0) at k=12.
        const int faA0 = q3 ? 0x3C00 : h2pack(tile[e + off0],      tile[e + off1]);
        const int faA1 = q3 ? 0      : h2pack(tile[e + off2],      tile[e + off3]);
        const int fbA0 = q3 ? 0x3C00 : h2pack(tile[e + off0 + 16], tile[e + off1 + 16]);
        const int fbA1 = q3 ? 0      : h2pack(tile[e + off2 + 16], tile[e + off3 + 16]);
        const int fcA0 = q3 ? 0x3C00 : h2pack(tile[e + off0 + 37], tile[e + off1 + 37]);
        const int fcA1 = q3 ? 0      : h2pack(tile[e + off2 + 37], tile[e + off3 + 37]);
        const int fdA0 = q3 ? 0x3C00 : h2pack(tile[e + off0 + 53], tile[e + off1 + 53]);
        const int fdA1 = q3 ? 0      : h2pack(tile[e + off2 + 53], tile[e + off3 + 53]);

        float pA, pB, pC, pD;
        asm volatile(
            "s_mov_b32 s21, 0x211f211f\n"
            "v_mov_b32 v32, 0\n" "v_mov_b32 v33, 0\n"
            "v_mov_b32 v34, 0\n" "v_mov_b32 v35, 0\n"
            "v_mov_b32 v36, %[fa0]\n" "v_mov_b32 v37, %[fa1]\n"
            "v_mov_b32 v38, %[fb0]\n" "v_mov_b32 v39, %[fb1]\n"
            "v_mov_b32 v40, %[fc0]\n" "v_mov_b32 v41, %[fc1]\n"
            "v_mov_b32 v42, %[fd0]\n" "v_mov_b32 v43, %[fd1]\n"
            MFA("w0") MFB("w0") MFC("w0") MFD("w0")
            "s_nop 7\n" "s_nop 7\n" "s_nop 7\n" "s_nop 4\n"
            LAYER("w1")  LAYER("w2")  LAYER("w3")  LAYER("w4")
            LAYER("w5")  LAYER("w6")  LAYER("w7")  LAYER("w8")
            LAYER("w9")  LAYER("w10") LAYER("w11") LAYER("w12")
            LAYER("w13") LAYER("w14") LAYER("w15")
            "v_mov_b32 %[pA], v44\n"
            "s_nop 1\n"
            "v_mov_b32 %[pB], v48\n"
            "s_nop 7\n" "s_nop 7\n"
            "v_mov_b32 %[pC], v52\n"
            "s_nop 3\n"
            "v_mov_b32 %[pD], v56\n"
            : [pA] "=v"(pA), [pB] "=v"(pB), [pC] "=v"(pC), [pD] "=v"(pD)
            : [w0] "a"(wq[0]),  [w1] "a"(wq[1]),  [w2] "a"(wq[2]),
              [w3] "a"(wq[3]),  [w4] "a"(wq[4]),  [w5] "a"(wq[5]),
              [w6] "a"(wq[6]),  [w7] "a"(wq[7]),  [w8] "a"(wq[8]),
              [w9] "a"(wq[9]),  [w10] "a"(wq[10]), [w11] "a"(wq[11]),
              [w12] "a"(wq[12]), [w13] "a"(wq[13]), [w14] "a"(wq[14]),
              [w15] "a"(wq[15]),
              [fa0] "v"(faA0), [fa1] "v"(faA1), [fb0] "v"(fbA0), [fb1] "v"(fbA1),
              [fc0] "v"(fcA0), [fc1] "v"(fcA1), [fd0] "v"(fdA0), [fd1] "v"(fdA1)
            : "s21",
              "v32","v33","v34","v35","v36","v37","v38","v39",
              "v40","v41","v42","v43","v44","v45","v46","v47",
              "v48","v49","v50","v51","v52","v53","v54","v55",
              "v56","v57","v58","v59","v60","v61");

        // raw pixels loaded after the asm to cap live regs at asm entry
        const float vA = tile[e],      vB = tile[e + 16];
        const float vC = tile[e + 37], vD = tile[e + 53];

        if (lane < 16) {                   // D row 0 = prediction, lanes 0..15
            const float qA = fminf(fmaxf(pA, -1.0f), 1.0f);
            const float uA = vA - qA + 1.0f;
            const float dA = uA - ((uA < 2.0f) ? 1.0f : 3.0f); // fmod(u,2)-1
            const float qB = fminf(fmaxf(pB, -1.0f), 1.0f);
            const float uB = vB - qB + 1.0f;
            const float dB = uB - ((uB < 2.0f) ? 1.0f : 3.0f);
            const float qC = fminf(fmaxf(pC, -1.0f), 1.0f);
            const float uC = vC - qC + 1.0f;
            const float dC = uC - ((uC < 2.0f) ? 1.0f : 3.0f);
            const float qD = fminf(fmaxf(pD, -1.0f), 1.0f);
            const float uD = vD - qD + 1.0f;
            const float dD = uD - ((uD < 2.0f) ? 1.0f : 3.0f);
            const int r = 2 * yi;
            stage[wv][r * 32 + t]            = dA;
            stage[wv][r * 32 + 16 + t]       = dB;
            stage[wv][(r + 1) * 32 + t]      = dC;
            stage[wv][(r + 1) * 32 + 16 + t] = dD;
            d2 = fmaf(dA, dA, fmaf(dB, dB, fmaf(dC, dC, fmaf(dD, dD, d2))));
        }
        e += 74;                            // two rows
    }

    // ---- coalesced delta store: wave's 256 floats = rows [8wv, 8wv+8) ----
    float* outp = out + 1 + (size_t)n * 1024 + wv * 256;
    #pragma unroll
    for (int j = 0; j < 4; ++j)
        outp[j * 64 + lane] = stage[wv][j * 64 + lane];

    // ---- loss reduction (d2 nonzero only in lanes 0..15) ----
    #pragma unroll
    for (int off = 8; off > 0; off >>= 1) d2 += __shfl_down(d2, off, 64);
    if (lane == 0) wsum[wv] = d2;
    __syncthreads();
    if (tid == 0) atomicAdd(loss_acc, wsum[0] + wsum[1] + wsum[2] + wsum[3]);
}

__global__ void codec_loss(const float* __restrict__ acc, float* __restrict__ out)
{
    out[0] = 255.0f * sqrtf(acc[0] / (float)NPIX);
}

extern "C" void kernel_launch(void* const* d_in, const int* in_sizes, int n_in,
                              void* d_out, int out_size, void* d_ws, size_t ws_size,
                              hipStream_t stream)
{
    const float* x  = (const float*)d_in[0];
    const float* Wh = (const float*)d_in[1];
    const float* bh = (const float*)d_in[2];
    const float* Wo = (const float*)d_in[3];
    const float* bo = (const float*)d_in[4];
    float* out = (float*)d_out;
    float* acc = (float*)d_ws;

    hipMemsetAsync(acc, 0, sizeof(float), stream);   // graph-capture safe
    codec_main<<<NBLK, 256, 0, stream>>>(x, Wh, bh, Wo, bo, out, acc);
    codec_loss<<<1, 1, 0, stream>>>(acc, out);
}